// Round 8
// baseline (27.146 us; speedup 1.0000x reference)
//
#include <hip/hip_runtime.h>

// Aspect-owned tiled 2-layer MLP, 2 dispatches, no atomics/fences.
//   gemm1:  grid (20 aspects, 4 col-slices, 8 d-slices) x 256 thr.
//           Block stages its W1 tile (96x64 fp32, unpadded, 24KB) in LDS once;
//           ALL waves redundantly ballot-scan the 1024 aspect_ids -> sidx
//           (padded to x16) with no extra barrier; then per 16-sample chunk:
//           X gathered into registers one chunk AHEAD (latency hidden under
//           compute), ds_write -> LDS, 4-sample x 4-col register blocking
//           (waves split K=96 into 4x24), LDS cross-wave reduce, write
//           disjoint pre-activation partials part[sample][dk][col]
//           (+b1 folded in at dk==0).
//   finish: per sample: sum 8 dk-partials, ReLU, x W2 + b2 -> out.

constexpr int D  = 768;
constexpr int H  = 256;
constexpr int NA = 20;
constexpr int NB = 1024;
constexpr int S  = 16;            // samples per chunk
constexpr int DKN = 8;            // d-slices
constexpr int KS  = D / DKN;      // 96 rows per block
constexpr int HSN = 4;            // 64-col slices
constexpr int KT  = KS / 4;       // 24 k per wave
constexpr int QR  = KS / 4;       // 24 float4 per staged x row
constexpr int XROW = KS + 4;      // 100 (pad; 400B stride -> 4 distinct banks)

// smem layout (float offsets)
constexpr int SM_XT   = KS * 64;             // w1t: [96][64]     = 6144
constexpr int SM_RED  = SM_XT + S * XROW;    // xt:  [16][100]    @6144
constexpr int SM_SIDX = SM_RED + 4096;       // red: [4][16][16]f4 @7744 (16KB)
constexpr int SM_TOT  = SM_SIDX + NB + S;    // sidx:[1024+16]    @11840
                                             // 12880 fl = 51.5 KB -> 3/CU
constexpr size_t WS_NEEDED = (size_t)NB * DKN * H * 4;   // part: 8 MB

__device__ __forceinline__ float4 fma4(float x, float4 w, float4 a) {
    a.x = fmaf(x, w.x, a.x); a.y = fmaf(x, w.y, a.y);
    a.z = fmaf(x, w.z, a.z); a.w = fmaf(x, w.w, a.w);
    return a;
}

__global__ __launch_bounds__(256, 3) void gemm1_kernel(
    const float* __restrict__ X,
    const int*   __restrict__ aids,
    const float* __restrict__ W1,
    const float* __restrict__ b1,
    float*       __restrict__ part)    // [NB][DKN][H]
{
    __shared__ __align__(16) float smem[SM_TOT];

    float*  w1t  = smem;
    float*  xt   = smem + SM_XT;
    float4* red4 = reinterpret_cast<float4*>(smem + SM_RED);
    int*    sidx = reinterpret_cast<int*>(smem + SM_SIDX);
    int*    ai   = reinterpret_cast<int*>(smem + SM_RED);   // prologue overlay

    const int t = threadIdx.x;
    const int w = t >> 6, l = t & 63;
    const int aid = blockIdx.x;        // aspect
    const int hs  = blockIdx.y;        // 64-col slice
    const int dk  = blockIdx.z;        // 96-row d-slice

    // issue W1 tile loads into registers (6 float4/thread, in flight during
    // the aid-stage + scan below)
    const float* W1s = W1 + (size_t)aid * D * H + (size_t)dk * KS * H + hs * 64;
    float4 wreg[6];
    #pragma unroll
    for (int i = 0; i < 6; ++i) {
        const int idx = t + i * 256;
        const int r = idx >> 4, cc = idx & 15;
        wreg[i] = *reinterpret_cast<const float4*>(&W1s[(size_t)r * H + cc * 4]);
    }

    // stage aspect ids (overlaid on red region)
    ai[t]       = aids[t];
    ai[t + 256] = aids[t + 256];
    ai[t + 512] = aids[t + 512];
    ai[t + 768] = aids[t + 768];
    __syncthreads();

    // ALL waves: redundant stable ballot-scan -> sidx (each wave reads only
    // its own writes afterwards -> no barrier needed)
    int run = 0;
    for (int base = 0; base < NB; base += 64) {
        const int id = ai[base + l];
        const unsigned long long m = __ballot(id == aid);
        const int pre = run + __popcll(m & ((1ull << l) - 1));
        if (id == aid) sidx[pre] = base + l;
        run += __popcll(m);
    }
    const int n = run;                 // uniform across block
    if (n == 0) return;                // aspect unused (uniform exit)

    // pad sidx[n .. ceil16(n)) with last valid id (removes clamps in gathers)
    {
        const int last = sidx[n - 1];  // own-wave write, hw-ordered
        const int npad = ((n + S - 1) / S) * S;
        if (l < S && n + l < npad) sidx[n + l] = last;
    }

    // commit W1 tile to LDS (unpadded linear: float4 slot == idx)
    float4* w1f4 = reinterpret_cast<float4*>(w1t);
    #pragma unroll
    for (int i = 0; i < 6; ++i) w1f4[t + i * 256] = wreg[i];

    const int sq = l >> 4;            // sample quad 0..3
    const int cq = l & 15;            // col quad 0..15
    const float* wb = w1t + (w * KT) * 64 + cq * 4;

    // register prefetch of chunk 0 (384 float4: thread t owns t and t+256)
    const int r0 = t / QR,         q0 = t - r0 * QR;
    const int j1 = t + 256;
    const int r1 = j1 / QR,        q1 = j1 - r1 * QR;
    float4 xr0, xr1;
    xr0 = *reinterpret_cast<const float4*>(
        &X[(size_t)sidx[r0] * D + dk * KS + q0 * 4]);
    if (t < S * QR - 256)
        xr1 = *reinterpret_cast<const float4*>(
            &X[(size_t)sidx[r1] * D + dk * KS + q1 * 4]);

    for (int ch = 0; ch * S < n; ++ch) {
        // commit staged X regs -> LDS
        *reinterpret_cast<float4*>(&xt[r0 * XROW + q0 * 4]) = xr0;
        if (t < S * QR - 256)
            *reinterpret_cast<float4*>(&xt[r1 * XROW + q1 * 4]) = xr1;
        __syncthreads();

        // issue next chunk's gathers (hide latency under compute)
        if ((ch + 1) * S < n) {
            const int b = (ch + 1) * S;
            xr0 = *reinterpret_cast<const float4*>(
                &X[(size_t)sidx[b + r0] * D + dk * KS + q0 * 4]);
            if (t < S * QR - 256)
                xr1 = *reinterpret_cast<const float4*>(
                    &X[(size_t)sidx[b + r1] * D + dk * KS + q1 * 4]);
        }

        // LDS x LDS compute: wave w covers k in [w*24, w*24+24)
        const float* xb = xt + (sq * 4) * XROW + w * KT;
        float4 a0 = {0,0,0,0}, a1 = {0,0,0,0}, a2 = {0,0,0,0}, a3 = {0,0,0,0};
        #pragma unroll
        for (int k4 = 0; k4 < KT; k4 += 4) {
            const float4 x0 = *reinterpret_cast<const float4*>(xb + k4);
            const float4 x1 = *reinterpret_cast<const float4*>(xb + XROW + k4);
            const float4 x2 = *reinterpret_cast<const float4*>(xb + 2 * XROW + k4);
            const float4 x3 = *reinterpret_cast<const float4*>(xb + 3 * XROW + k4);
            const float* wp = wb + k4 * 64;
            float4 wv;
            wv = *reinterpret_cast<const float4*>(wp);
            a0 = fma4(x0.x, wv, a0); a1 = fma4(x1.x, wv, a1);
            a2 = fma4(x2.x, wv, a2); a3 = fma4(x3.x, wv, a3);
            wv = *reinterpret_cast<const float4*>(wp + 64);
            a0 = fma4(x0.y, wv, a0); a1 = fma4(x1.y, wv, a1);
            a2 = fma4(x2.y, wv, a2); a3 = fma4(x3.y, wv, a3);
            wv = *reinterpret_cast<const float4*>(wp + 128);
            a0 = fma4(x0.z, wv, a0); a1 = fma4(x1.z, wv, a1);
            a2 = fma4(x2.z, wv, a2); a3 = fma4(x3.z, wv, a3);
            wv = *reinterpret_cast<const float4*>(wp + 192);
            a0 = fma4(x0.w, wv, a0); a1 = fma4(x1.w, wv, a1);
            a2 = fma4(x2.w, wv, a2); a3 = fma4(x3.w, wv, a3);
        }

        // cross-wave reduce
        red4[(w * 16 + sq * 4 + 0) * 16 + cq] = a0;
        red4[(w * 16 + sq * 4 + 1) * 16 + cq] = a1;
        red4[(w * 16 + sq * 4 + 2) * 16 + cq] = a2;
        red4[(w * 16 + sq * 4 + 3) * 16 + cq] = a3;
        __syncthreads();

        {
            const int s = t >> 4, q = t & 15;
            const int cv = min(S, n - ch * S);
            float4 v = red4[s * 16 + q];
            #pragma unroll
            for (int ww = 1; ww < 4; ++ww) {
                const float4 r = red4[ww * 256 + s * 16 + q];
                v.x += r.x; v.y += r.y; v.z += r.z; v.w += r.w;
            }
            if (s < cv) {
                if (dk == 0) {      // fold b1 exactly once
                    const float4 bv = *reinterpret_cast<const float4*>(
                        &b1[(size_t)aid * H + hs * 64 + q * 4]);
                    v.x += bv.x; v.y += bv.y; v.z += bv.z; v.w += bv.w;
                }
                const int sid = sidx[ch * S + s];
                *reinterpret_cast<float4*>(
                    &part[((size_t)sid * DKN + dk) * H + hs * 64 + q * 4]) = v;
            }
        }
        // next iteration's xt writes are safe: reduce touches red4 only, and
        // the following __syncthreads orders red4 reuse.
    }
}

__global__ __launch_bounds__(256) void finish_kernel(
    const int*   __restrict__ aids,
    const float* __restrict__ part,
    const float* __restrict__ W2,
    const float* __restrict__ b2,
    float*       __restrict__ out)
{
    const int w = threadIdx.x >> 6, l = threadIdx.x & 63;
    const int s = blockIdx.x * 4 + w;       // one sample per wave
    const int aid = aids[s];

    const float* ps = part + (size_t)s * DKN * H + l * 4;
    float4 v = {0,0,0,0};
    #pragma unroll
    for (int dk = 0; dk < DKN; ++dk) {
        const float4 r = *reinterpret_cast<const float4*>(ps + dk * H);
        v.x += r.x; v.y += r.y; v.z += r.z; v.w += r.w;
    }
    float4 o;
    o.x = fmaxf(v.x, 0.f);
    o.y = fmaxf(v.y, 0.f);
    o.z = fmaxf(v.z, 0.f);
    o.w = fmaxf(v.w, 0.f);

    const float4* W2v = reinterpret_cast<const float4*>(&W2[(size_t)aid * H * 2 + l * 8]);
    const float4 w2a = W2v[0], w2b = W2v[1];
    float p0 = o.x * w2a.x + o.y * w2a.z + o.z * w2b.x + o.w * w2b.z;
    float p1 = o.x * w2a.y + o.y * w2a.w + o.z * w2b.y + o.w * w2b.w;
    #pragma unroll
    for (int m = 1; m < 64; m <<= 1) {
        p0 += __shfl_xor(p0, m, 64);
        p1 += __shfl_xor(p1, m, 64);
    }
    if (l == 0) {
        const float2 bias2 = reinterpret_cast<const float2*>(b2)[aid];
        reinterpret_cast<float2*>(out)[s] = make_float2(p0 + bias2.x, p1 + bias2.y);
    }
}

// ---------------- fallback (round-1 monolithic kernel) ----------------
__global__ __launch_bounds__(256, 4) void aspect_mlp_fallback(
    const float* __restrict__ X, const int* __restrict__ aspect_ids,
    const float* __restrict__ W1_embs, const float* __restrict__ b1_embs,
    const float* __restrict__ W2_embs, const float* __restrict__ b2_embs,
    float* __restrict__ out)
{
    __shared__ float xs[D];
    __shared__ float pl[4][H];
    __shared__ float red[4][2];
    const int b = blockIdx.x, t = threadIdx.x, w = t >> 6, l = t & 63;
    const int aid = aspect_ids[b];
    const float4* Xr = reinterpret_cast<const float4*>(X + (size_t)b * D);
    if (t < D / 4) reinterpret_cast<float4*>(xs)[t] = Xr[t];
    __syncthreads();
    const float4* W1v = reinterpret_cast<const float4*>(W1_embs + (size_t)aid * (D * H));
    float4 acc = make_float4(0.f, 0.f, 0.f, 0.f);
    const int d0 = w * (D / 4);
    for (int d = d0; d < d0 + D / 4; ++d) {
        const float xv = xs[d];
        const float4 wv = W1v[d * (H / 4) + l];
        acc.x = fmaf(xv, wv.x, acc.x); acc.y = fmaf(xv, wv.y, acc.y);
        acc.z = fmaf(xv, wv.z, acc.z); acc.w = fmaf(xv, wv.w, acc.w);
    }
    reinterpret_cast<float4*>(pl[w])[l] = acc;
    __syncthreads();
    const float o = fmaxf(pl[0][t] + pl[1][t] + pl[2][t] + pl[3][t] + b1_embs[aid * H + t], 0.f);
    const float2 w2 = reinterpret_cast<const float2*>(W2_embs)[aid * H + t];
    float p0 = o * w2.x, p1 = o * w2.y;
    for (int s = 32; s; s >>= 1) { p0 += __shfl_xor(p0, s, 64); p1 += __shfl_xor(p1, s, 64); }
    if (l == 0) { red[w][0] = p0; red[w][1] = p1; }
    __syncthreads();
    if (t == 0) {
        const float2 bias2 = reinterpret_cast<const float2*>(b2_embs)[aid];
        out[b * 2 + 0] = red[0][0] + red[1][0] + red[2][0] + red[3][0] + bias2.x;
        out[b * 2 + 1] = red[0][1] + red[1][1] + red[2][1] + red[3][1] + bias2.y;
    }
}

extern "C" void kernel_launch(void* const* d_in, const int* in_sizes, int n_in,
                              void* d_out, int out_size, void* d_ws, size_t ws_size,
                              hipStream_t stream) {
    const float* X          = (const float*)d_in[0];
    const int*   aspect_ids = (const int*)d_in[1];
    const float* W1_embs    = (const float*)d_in[2];
    const float* b1_embs    = (const float*)d_in[3];
    const float* W2_embs    = (const float*)d_in[4];
    const float* b2_embs    = (const float*)d_in[5];
    float*       out        = (float*)d_out;

    const int Brt = in_sizes[0] / D;
    const int na  = in_sizes[2] / (D * H);

    if (Brt != NB || na != NA || ws_size < WS_NEEDED) {
        aspect_mlp_fallback<<<Brt, 256, 0, stream>>>(
            X, aspect_ids, W1_embs, b1_embs, W2_embs, b2_embs, out);
        return;
    }

    float* part = (float*)d_ws;

    gemm1_kernel<<<dim3(NA, HSN, DKN), 256, 0, stream>>>(
        X, aspect_ids, W1_embs, b1_embs, part);
    finish_kernel<<<NB / 4, 256, 0, stream>>>(
        aspect_ids, part, W2_embs, b2_embs, out);
}